// Round 1
// 127.522 us; speedup vs baseline: 1.0752x; 1.0752x over previous
//
#include <hip/hip_runtime.h>

#define N_NODES 8192
#define DIM     128
#define N_COMM  100
#define MARGIN  1.0f

// minneg: 128x128 block tile, 4 waves of 64x64, mfma 32x32x16 bf16, K staged
// in 32-wide quarters. LDS stride 40 shorts = 80 B = 5*16B.
// T14 async-STAGE: next-kq global loads issued before the MFMA phase, written
// to LDS after the next barrier -> L2 latency hides under compute.
#define KQ       32
#define LDS_STR  40
#define RP_STR   68               // row-min partial stride (floats)

typedef __attribute__((ext_vector_type(8)))  short bf16x8;
typedef __attribute__((ext_vector_type(16))) float f32x16;

__device__ inline unsigned short f32_to_bf16_rne(float f) {
    unsigned u = __float_as_uint(f);
    unsigned r = u + 0x7fffu + ((u >> 16) & 1u);
    return (unsigned short)(r >> 16);
}
__device__ inline float bf16_to_f32(unsigned short h) {
    return __uint_as_float(((unsigned)h) << 16);
}

// ---------------------------------------------------------------------------
// Kernel 0 (merged): blocks 0..2047 = bf16 hi/lo split + row sq norms + min_d2
// init (wave per row); block 2048 = community bucketing + psum/pcnt zeroing.
__global__ __launch_bounds__(256)
void prep_kernel(const float* __restrict__ x,
                 const int* __restrict__ comm,
                 unsigned short* __restrict__ xhi,
                 unsigned short* __restrict__ xlo,
                 float* __restrict__ sq,
                 unsigned int* __restrict__ min_d2,
                 int* __restrict__ offs,
                 int* __restrict__ members,
                 double* __restrict__ psum,
                 unsigned int* __restrict__ pcnt) {
    __shared__ int scnt[N_COMM];
    __shared__ int scur[N_COMM];
    const int tid = threadIdx.x;

    if (blockIdx.x < 2048) {
        int row  = blockIdx.x * 4 + (tid >> 6);
        int lane = tid & 63;
        const float* p = x + (size_t)row * DIM;
        float v0 = p[lane], v1 = p[lane + 64];
        unsigned short h0 = f32_to_bf16_rne(v0), h1 = f32_to_bf16_rne(v1);
        unsigned short l0 = f32_to_bf16_rne(v0 - bf16_to_f32(h0));
        unsigned short l1 = f32_to_bf16_rne(v1 - bf16_to_f32(h1));
        size_t base = (size_t)row * DIM;
        xhi[base + lane] = h0;  xhi[base + 64 + lane] = h1;
        xlo[base + lane] = l0;  xlo[base + 64 + lane] = l1;
        float s = v0 * v0 + v1 * v1;
        #pragma unroll
        for (int off = 32; off > 0; off >>= 1) s += __shfl_down(s, off);
        if (lane == 0) {
            sq[row] = s;
            min_d2[row] = 0x7f800000u;   // +inf bits
        }
        return;
    }

    // ---- bucketing block
    if (tid < N_COMM) {
        scnt[tid] = 0;
        psum[tid] = 0.0;      // pos kernel now accumulates -> zero each launch
        pcnt[tid] = 0u;
    }
    __syncthreads();
    for (int i = tid; i < N_NODES; i += 256) atomicAdd(&scnt[comm[i]], 1);
    __syncthreads();
    if (tid == 0) {
        int acc = 0;
        for (int c = 0; c < N_COMM; ++c) { scur[c] = acc; offs[c] = acc; acc += scnt[c]; }
        offs[N_COMM] = acc;
    }
    __syncthreads();
    for (int i = tid; i < N_NODES; i += 256) {
        int p = atomicAdd(&scur[comm[i]], 1);
        members[p] = i;
    }
}

// ---------------------------------------------------------------------------
// Kernel 1: MFMA X·X^T (bf16 hi/lo), exact triangular grid (2080 blocks),
// K staged in 32-quarters (41.4 KB LDS -> 3 blocks/CU), col-min AND row-min.
// C/D layout (m74/m101): col = lane&31, row = (reg&3) + 8*(reg>>2) + 4*(lane>>5).
__device__ __forceinline__ uint4 mn_load(const unsigned short* __restrict__ xhi,
                                         const unsigned short* __restrict__ xlo,
                                         int i0, int j0, int tid, int it, int kq) {
    int g    = tid + it * 256;          // 0..2047
    int tile = g >> 9;                  // 0..3
    int row  = (g >> 2) & 127;
    int seg  = g & 3;
    const unsigned short* src = (tile & 1) ? xlo : xhi;
    int rbase = (tile & 2) ? j0 : i0;
    return *(const uint4*)&src[(size_t)(rbase + row) * DIM + kq * KQ + seg * 8];
}

__global__ __launch_bounds__(256, 3)
void minneg_mfma_kernel(const unsigned short* __restrict__ xhi,
                        const unsigned short* __restrict__ xlo,
                        const int* __restrict__ comm,
                        const float* __restrict__ sq,
                        unsigned int* __restrict__ min_d2) {
    __shared__ __align__(16) unsigned short lds[4][128][LDS_STR];  // 40960 B
    __shared__ unsigned int colmin[128];

    // linear -> lower-triangle (bx >= by)
    const int b = blockIdx.x;
    int bx = (int)((sqrtf(8.f * (float)b + 1.f) - 1.f) * 0.5f);
    while ((bx + 1) * (bx + 2) / 2 <= b) ++bx;
    while (bx * (bx + 1) / 2 > b) --bx;
    const int by = b - bx * (bx + 1) / 2;

    const int tid  = threadIdx.x;
    const int lane = tid & 63;
    const int w    = tid >> 6;
    const int wr   = w >> 1, wc = w & 1;
    const int lr   = lane & 31;
    const int lh   = lane >> 5;
    const int i0   = bx * 128;      // A rows
    const int j0   = by * 128;      // B rows (= output cols)

    if (tid < 128) colmin[tid] = 0x7f800000u;

    f32x16 acc[2][2];
    #pragma unroll
    for (int g = 0; g < 2; ++g)
        #pragma unroll
        for (int h = 0; h < 2; ++h)
            #pragma unroll
            for (int e = 0; e < 16; ++e) acc[g][h][e] = 0.f;

    // T14 prologue: kq=0 tile into registers
    uint4 v[8];
    #pragma unroll
    for (int it = 0; it < 8; ++it) v[it] = mn_load(xhi, xlo, i0, j0, tid, it, 0);

    #pragma unroll
    for (int kq = 0; kq < 4; ++kq) {
        __syncthreads();    // previous compute done reading LDS (drains v's loads)
        #pragma unroll
        for (int it = 0; it < 8; ++it) {
            int g    = tid + it * 256;
            int tile = g >> 9;
            int row  = (g >> 2) & 127;
            int seg  = g & 3;
            *(uint4*)&lds[tile][row][seg * 8] = v[it];
        }
        __syncthreads();

        // issue next quarter's loads now; consumed at next top-of-loop write.
        if (kq < 3) {
            #pragma unroll
            for (int it = 0; it < 8; ++it)
                v[it] = mn_load(xhi, xlo, i0, j0, tid, it, kq + 1);
        }

        #pragma unroll
        for (int ks = 0; ks < 2; ++ks) {
            const int kb = ks * 16 + lh * 8;
            bf16x8 ahi[2], alo[2], bhi[2], blo[2];
            #pragma unroll
            for (int g = 0; g < 2; ++g) {
                ahi[g] = *(const bf16x8*)&lds[0][wr * 64 + g * 32 + lr][kb];
                alo[g] = *(const bf16x8*)&lds[1][wr * 64 + g * 32 + lr][kb];
            }
            #pragma unroll
            for (int h = 0; h < 2; ++h) {
                bhi[h] = *(const bf16x8*)&lds[2][wc * 64 + h * 32 + lr][kb];
                blo[h] = *(const bf16x8*)&lds[3][wc * 64 + h * 32 + lr][kb];
            }
            #pragma unroll
            for (int g = 0; g < 2; ++g)
                #pragma unroll
                for (int h = 0; h < 2; ++h) {
                    acc[g][h] = __builtin_amdgcn_mfma_f32_32x32x16_bf16(
                        ahi[g], bhi[h], acc[g][h], 0, 0, 0);
                    acc[g][h] = __builtin_amdgcn_mfma_f32_32x32x16_bf16(
                        ahi[g], blo[h], acc[g][h], 0, 0, 0);
                    acc[g][h] = __builtin_amdgcn_mfma_f32_32x32x16_bf16(
                        alo[g], bhi[h], acc[g][h], 0, 0, 0);
                }
        }
    }

    // ---- epilogue: d2 = sq_i + sq_j - 2*dot ; col-min AND row-min over negatives
    int   civ[2][4][4];
    float sqv[2][4][4];
    #pragma unroll
    for (int g = 0; g < 2; ++g)
        #pragma unroll
        for (int q = 0; q < 4; ++q) {
            int rb = i0 + wr * 64 + g * 32 + 4 * lh + 8 * q;
            *(int4*)&civ[g][q][0]   = *(const int4*)&comm[rb];
            *(float4*)&sqv[g][q][0] = *(const float4*)&sq[rb];
        }

    const float FINF = __uint_as_float(0x7f800000u);
    float rmin[2][16];
    #pragma unroll
    for (int g = 0; g < 2; ++g)
        #pragma unroll
        for (int e = 0; e < 16; ++e) rmin[g][e] = FINF;

    #pragma unroll
    for (int h = 0; h < 2; ++h) {
        int colt = wc * 64 + h * 32 + lr;
        int j  = j0 + colt;
        int cj = comm[j];
        float sqj = sq[j];
        float cmin = FINF;
        #pragma unroll
        for (int g = 0; g < 2; ++g)
            #pragma unroll
            for (int q = 0; q < 4; ++q)
                #pragma unroll
                for (int t = 0; t < 4; ++t) {
                    float d2 = fmaxf(sqv[g][q][t] + sqj - 2.f * acc[g][h][q * 4 + t], 0.f);
                    if (civ[g][q][t] != cj) {
                        cmin = fminf(cmin, d2);
                        rmin[g][q * 4 + t] = fminf(rmin[g][q * 4 + t], d2);
                    }
                }
        cmin = fminf(cmin, __shfl_xor(cmin, 32));
        if (lh == 0) atomicMin(&colmin[colt], __float_as_uint(cmin));
    }

    // row-min: scatter per-thread partials into LDS overlay, then 128-thread reduce
    __syncthreads();
    float (*rowpart)[RP_STR] = (float (*)[RP_STR])lds;   // 128 x 68 floats (34.8 KB)
    #pragma unroll
    for (int g = 0; g < 2; ++g)
        #pragma unroll
        for (int q = 0; q < 4; ++q)
            #pragma unroll
            for (int t = 0; t < 4; ++t) {
                int rowl = wr * 64 + g * 32 + 4 * lh + 8 * q + t;
                rowpart[rowl][wc * 32 + lr] = rmin[g][q * 4 + t];
            }
    __syncthreads();
    if (tid < 128) {
        float m = FINF;
        #pragma unroll
        for (int k = 0; k < 16; ++k) {
            float4 vv = *(const float4*)&rowpart[tid][k * 4];
            m = fminf(m, fminf(fminf(vv.x, vv.y), fminf(vv.z, vv.w)));
        }
        atomicMin(&min_d2[i0 + tid], __float_as_uint(m));
        atomicMin(&min_d2[j0 + tid], colmin[tid]);
    }
}

// ---------------------------------------------------------------------------
// Kernel 2: positives, wave-parallel. One WAVE per (community, 32x32 tile-pair):
// no LDS, no barriers; mfma fragments loaded straight from global (L2-hot,
// xhi+xlo = 4 MB total). A/B frag layout for 32x32x16: row/col = lane&31,
// k = 8*(lane>>5)+i -> lane loads 16 B from its row at k-offset. ~900 active
// waves vs the old 400 (and those were barrier-locked in 100 blocks).
__global__ __launch_bounds__(256)
void pos_wave_kernel(const unsigned short* __restrict__ xhi,
                     const unsigned short* __restrict__ xlo,
                     const float* __restrict__ sq,
                     const unsigned int* __restrict__ min_d2,
                     const int* __restrict__ offs,
                     const int* __restrict__ members,
                     double* __restrict__ psum,
                     unsigned int* __restrict__ pcnt) {
    const int c    = blockIdx.x >> 2;                     // 4 blocks/community
    const int tid  = threadIdx.x;
    const int lane = tid & 63;
    const int lr   = lane & 31;
    const int lh   = lane >> 5;
    const int wsub = ((blockIdx.x & 3) << 2) | (tid >> 6);  // 0..15

    const int beg  = offs[c], end = offs[c + 1];
    const int size = end - beg;
    if (size <= 0) return;
    const int m = (size + 31) >> 5;                       // 32-row tiles

    float tsum = 0.f;
    unsigned int tcnt = 0u;

    for (int idx = wsub; idx < m * m; idx += 16) {
        int ti = idx / m, tj = idx - ti * m;
        int s0 = ti * 32, t0 = tj * 32;
        int slotA = s0 + lr, slotB = t0 + lr;
        int nodeA = members[beg + (slotA < size ? slotA : size - 1)];
        int nodeB = members[beg + (slotB < size ? slotB : size - 1)];

        // epilogue operands issued early to hide latency under the MFMA loop
        float sqa_own = sq[nodeA];
        unsigned mb = min_d2[nodeA];
        float mn_own = (mb == 0x7f800000u) ? -1.f
                     : sqrtf(fmaxf(__uint_as_float(mb), 0.f));
        float sqb = sq[nodeB];

        const unsigned short* pAh = xhi + (size_t)nodeA * DIM;
        const unsigned short* pAl = xlo + (size_t)nodeA * DIM;
        const unsigned short* pBh = xhi + (size_t)nodeB * DIM;
        const unsigned short* pBl = xlo + (size_t)nodeB * DIM;

        f32x16 a0, a1, a2;   // 3 independent chains (hi*hi, hi*lo, lo*hi)
        #pragma unroll
        for (int e = 0; e < 16; ++e) { a0[e] = 0.f; a1[e] = 0.f; a2[e] = 0.f; }

        #pragma unroll
        for (int ks = 0; ks < 8; ++ks) {
            const int ko = ks * 16 + lh * 8;
            bf16x8 ahi = *(const bf16x8*)&pAh[ko];
            bf16x8 alo = *(const bf16x8*)&pAl[ko];
            bf16x8 bhi = *(const bf16x8*)&pBh[ko];
            bf16x8 blo = *(const bf16x8*)&pBl[ko];
            a0 = __builtin_amdgcn_mfma_f32_32x32x16_bf16(ahi, bhi, a0, 0, 0, 0);
            a1 = __builtin_amdgcn_mfma_f32_32x32x16_bf16(ahi, blo, a1, 0, 0, 0);
            a2 = __builtin_amdgcn_mfma_f32_32x32x16_bf16(alo, bhi, a2, 0, 0, 0);
        }

        #pragma unroll
        for (int q = 0; q < 4; ++q)
            #pragma unroll
            for (int t = 0; t < 4; ++t) {
                int r = 4 * lh + 8 * q + t;          // output row within tile
                float sqa = __shfl(sqa_own, r);      // lane r holds row r's values
                float mn  = __shfl(mn_own, r);
                int e = q * 4 + t;
                if ((s0 + r < size) && (slotB < size) &&
                    (s0 + r != slotB) && (mn >= 0.f)) {
                    float dot  = a0[e] + a1[e] + a2[e];
                    float d2   = sqa + sqb - 2.f * dot;
                    float dist = sqrtf(fmaxf(d2, 0.f));
                    tsum += fmaxf(dist - mn + MARGIN, 0.f);
                    tcnt += 1u;
                }
            }
    }

    #pragma unroll
    for (int off = 32; off > 0; off >>= 1) {
        tsum += __shfl_down(tsum, off);
        tcnt += __shfl_down(tcnt, off);
    }
    if (lane == 0 && tcnt > 0u) {
        atomicAdd(&psum[c], (double)tsum);
        atomicAdd(&pcnt[c], tcnt);
    }
}

// ---------------------------------------------------------------------------
// Kernel 3: reduce 100 community partials -> final mean.
__global__ __launch_bounds__(256)
void finalize_kernel(const double* __restrict__ psum,
                     const unsigned int* __restrict__ pcnt,
                     float* __restrict__ out) {
    __shared__ double       ds[256];
    __shared__ unsigned int cs[256];
    const int t = threadIdx.x;
    double s = 0.0; unsigned int c = 0u;
    for (int b = t; b < N_COMM; b += 256) { s += psum[b]; c += pcnt[b]; }
    ds[t] = s; cs[t] = c;
    __syncthreads();
    for (int off = 128; off > 0; off >>= 1) {
        if (t < off) { ds[t] += ds[t + off]; cs[t] += cs[t + off]; }
        __syncthreads();
    }
    if (t == 0) out[0] = (cs[0] > 0u) ? (float)(ds[0] / (double)cs[0]) : 0.f;
}

// ---------------------------------------------------------------------------
extern "C" void kernel_launch(void* const* d_in, const int* in_sizes, int n_in,
                              void* d_out, int out_size, void* d_ws, size_t ws_size,
                              hipStream_t stream) {
    const float* x    = (const float*)d_in[0];
    const int*   comm = (const int*)d_in[1];
    float*       out  = (float*)d_out;

    // workspace layout (bytes):
    //       0 float  sq[8192]           32768
    //   32768 uint   min_d2[8192]       32768
    //   65536 int    offs[101]            512 (padded)
    //   66048 int    members[8192]      32768
    //   98816 double psum[100]           1024 (padded)
    //   99840 uint   pcnt[100]            512 (padded)
    //  100352 ushort xhi[8192*128]    2097152
    // 2197504 ushort xlo[8192*128]    2097152   (total ~4.1 MB)
    char* ws = (char*)d_ws;
    float*          sq      = (float*)(ws);
    unsigned int*   min_d2  = (unsigned int*)(ws + 32768);
    int*            offs    = (int*)(ws + 65536);
    int*            members = (int*)(ws + 66048);
    double*         psum    = (double*)(ws + 98816);
    unsigned int*   pcnt    = (unsigned int*)(ws + 99840);
    unsigned short* xhi     = (unsigned short*)(ws + 100352);
    unsigned short* xlo     = (unsigned short*)(ws + 2197504);

    prep_kernel<<<2049, 256, 0, stream>>>(x, comm, xhi, xlo, sq, min_d2,
                                          offs, members, psum, pcnt);

    const int ntri = (N_NODES / 128) * (N_NODES / 128 + 1) / 2;   // 2080
    minneg_mfma_kernel<<<ntri, 256, 0, stream>>>(xhi, xlo, comm, sq, min_d2);

    pos_wave_kernel<<<N_COMM * 4, 256, 0, stream>>>(xhi, xlo, sq, min_d2, offs,
                                                    members, psum, pcnt);

    finalize_kernel<<<1, 256, 0, stream>>>(psum, pcnt, out);
}